// Round 17
// baseline (157.392 us; speedup 1.0000x reference)
//
#include <hip/hip_runtime.h>
#include <stdint.h>

// ---------------- types & helpers ----------------
typedef short sh4 __attribute__((ext_vector_type(4)));
typedef short short8 __attribute__((ext_vector_type(8)));
typedef float f32x4 __attribute__((ext_vector_type(4)));
typedef _Float16 half4 __attribute__((ext_vector_type(4)));
typedef _Float16 half8 __attribute__((ext_vector_type(8)));
typedef unsigned int uint2v __attribute__((ext_vector_type(2)));

__device__ __forceinline__ short f2h(float f) {
    _Float16 h = (_Float16)f;
    return __builtin_bit_cast(short, h);
}

__device__ __forceinline__ f32x4 mfma_k32(short8 a, short8 b, f32x4 c) {
    return __builtin_amdgcn_mfma_f32_16x16x32_f16(
        __builtin_bit_cast(half8, a), __builtin_bit_cast(half8, b), c, 0, 0, 0);
}
__device__ __forceinline__ f32x4 mfma_k16(half4 a, half4 b, f32x4 c) {
    return __builtin_amdgcn_mfma_f32_16x16x16f16(a, b, c, 0, 0, 0);
}
__device__ __forceinline__ unsigned int pkrtz(float a, float b) {
    return __builtin_bit_cast(unsigned int, __builtin_amdgcn_cvt_pkrtz(a, b));
}
__device__ __forceinline__ float exp2_raw(float x) {
    float r;
    asm("v_exp_f32 %0, %1" : "=v"(r) : "v"(x));   // 2^x, single instr
    return r;
}

// Problem constants: B=4, C=256, H=W=128 (PX=16384), inner=256, heads=8, c/head=32,
// patch=8 -> keys=256, conv K-dim = 256*64 = 16384.
// NOTE (r6/r14): exp shift must be the exact row max from the logits.
// NOTE (r9-r11): f16 logit stash -> wrong results (bisected). TWO-PASS QK^T;
//   pitch-40 K staging was EXONERATED by the r11 bisect (failure persisted
//   without it) and is used below to fix the 8-way Kl bank conflict.
// NOTE (r9 vs r10): ones-row MFMA denominator == shfl-sum (bit-identical);
//   ones-row is correct and used (VALU -> MFMA shift), verified passing r16.
// NOTE (r13): keeping both nt P-arrays live halves occupancy. nt sequential.
// NOTE (r16): q is PRE-SCALED by log2(e) in k_q_gemm -> raw v_exp_f32 in attn.

// ---------------- pack kernels: 64x64 fp32 tile transpose -> f16 ----------------
__device__ __forceinline__ void transpose64(const float* __restrict__ src,
                                            short* __restrict__ dst,
                                            int srcSlowStride, int dstRowStride) {
    __shared__ float tile[64][65];
    const int t = threadIdx.x;
#pragma unroll
    for (int i = 0; i < 16; ++i) {
        int idx = i * 256 + t;
        int fast = idx & 63, slow = idx >> 6;
        tile[slow][fast] = src[(long)slow * srcSlowStride + fast];
    }
    __syncthreads();
#pragma unroll
    for (int i = 0; i < 2; ++i) {
        int ch = i * 256 + t;
        int fast = ch >> 3, sg = ch & 7;
        short8 v;
#pragma unroll
        for (int j = 0; j < 8; ++j) v[j] = f2h(tile[sg * 8 + j][fast]);
        *(short8*)(dst + (long)fast * dstRowStride + sg * 8) = v;
    }
}

// x: [4][256][16384] fp32 (NCHW) -> xn: [4][16384][256] f16 (NHWC)
__global__ __launch_bounds__(256) void k_pack_x(const float* __restrict__ x,
                                                short* __restrict__ xn) {
    int bi = blockIdx.x;                 // 4096 = 4b * 256pxt * 4ct
    int ct = bi & 3, pxt = (bi >> 2) & 255, b = bi >> 10;
    const float* src = x + (((long)(b * 256 + ct * 64)) << 14) + (long)pxt * 64;
    short* dst = xn + (((long)(b << 14) + pxt * 64) * 256) + ct * 64;
    transpose64(src, dst, 16384, 256);
}

// Wk/Wv: [256][256][64] fp32 -> wp: [512][64][256] f16 (oc<256: k, else v), K order (dydx, c)
__global__ __launch_bounds__(256) void k_pack_w(const float* __restrict__ wk,
                                                const float* __restrict__ wv,
                                                short* __restrict__ wp) {
    int bi = blockIdx.x;                 // 2048 = 512oc * 4ct
    int ct = bi & 3, oc = bi >> 2;
    const float* base = (oc < 256) ? (wk + (long)oc * 16384) : (wv + (long)(oc - 256) * 16384);
    const float* src = base + ct * 4096; // + c0*64
    short* dst = wp + (long)oc * 16384 + ct * 64;
    transpose64(src, dst, 64, 256);
}

// Wq: [256][256] fp32 -> f16 (layout preserved: [oc][c])
__global__ __launch_bounds__(256) void k_pack_wq(const float* __restrict__ wq,
                                                 short* __restrict__ wqp) {
    int i = blockIdx.x * 256 + threadIdx.x; // grid 256 -> 65536
    wqp[i] = f2h(wq[i]);
}

// ---------------- K/V conv as GEMM (v4: 64x64 tile, 1024 blocks, 4/CU) ----
// C[patch 1024][oc 512] = A[patch][k 16384] * B[k][oc]
// grid 1024 = 8kc * 16pm * 8nb; block 256 thr (4 waves); Kchunk 2048 (32 x BK=64).
// 4 blocks/CU so staging/barrier phases of one block overlap compute of others.
__global__ __launch_bounds__(256) void k_kv_gemm(const short* __restrict__ xn,
                                                 const short* __restrict__ wp,
                                                 float* __restrict__ part) {
    __shared__ short Al[64 * 64]; // rows 128B = 8 granules, swizzled
    __shared__ short Bl[64 * 64];
    int bid = blockIdx.x;                       // 1024
    int wg = (bid & 7) * 128 + (bid >> 3);      // XCD-contiguous swizzle (1024 = 8*128)
    int nb = wg & 7, pm = (wg >> 3) & 15, kc = wg >> 7;
    int t = threadIdx.x, l = t & 63, w = t >> 6;
    int wm = w >> 1, wn = w & 1;
    int low = l & 15, q = l >> 4;

    f32x4 acc[2][2];
#pragma unroll
    for (int mt = 0; mt < 2; ++mt)
#pragma unroll
        for (int nt = 0; nt < 2; ++nt) acc[mt][nt] = (f32x4){0.f, 0.f, 0.f, 0.f};

    for (int kk = 0; kk < 32; ++kk) {
        short8 va[2], vb[2];
#pragma unroll
        for (int i = 0; i < 2; ++i) {           // A: 512 granules (64 rows x 8)
            int g = i * 256 + t;
            int row = g >> 3, lg = g & 7;
            int patch = pm * 64 + row;
            int kg = kc * 2048 + kk * 64 + lg * 8;
            int dydx = kg >> 8, cc = kg & 255;
            int bb = patch >> 8, pid = patch & 255;
            int ph = pid >> 4, pw = pid & 15;
            int px = (ph * 8 + (dydx >> 3)) * 128 + pw * 8 + (dydx & 7);
            va[i] = *(const short8*)(xn + ((long)(bb << 14) + px) * 256 + cc);
        }
#pragma unroll
        for (int i = 0; i < 2; ++i) {           // B: 512 granules (64 rows x 8)
            int g = i * 256 + t;
            int row = g >> 3, lg = g & 7;
            int oc = nb * 64 + row;
            int kg = kc * 2048 + kk * 64 + lg * 8;
            vb[i] = *(const short8*)(wp + (long)oc * 16384 + kg);
        }
#pragma unroll
        for (int i = 0; i < 2; ++i) {
            int g = i * 256 + t;
            int row = g >> 3, lg = g & 7;
            *(short8*)(Al + row * 64 + ((lg ^ (row & 7)) * 8)) = va[i];
        }
#pragma unroll
        for (int i = 0; i < 2; ++i) {
            int g = i * 256 + t;
            int row = g >> 3, lg = g & 7;
            *(short8*)(Bl + row * 64 + ((lg ^ (row & 7)) * 8)) = vb[i];
        }
        __syncthreads();
#pragma unroll
        for (int ks = 0; ks < 2; ++ks) {
            short8 af[2], bf[2];
#pragma unroll
            for (int mt = 0; mt < 2; ++mt) {
                int row = wm * 32 + mt * 16 + low;
                int lg = ks * 4 + q;
                af[mt] = *(const short8*)(Al + row * 64 + ((lg ^ (row & 7)) * 8));
            }
#pragma unroll
            for (int nt = 0; nt < 2; ++nt) {
                int row = wn * 32 + nt * 16 + low;
                int lg = ks * 4 + q;
                bf[nt] = *(const short8*)(Bl + row * 64 + ((lg ^ (row & 7)) * 8));
            }
#pragma unroll
            for (int mt = 0; mt < 2; ++mt)
#pragma unroll
                for (int nt = 0; nt < 2; ++nt)
                    acc[mt][nt] = mfma_k32(af[mt], bf[nt], acc[mt][nt]);
        }
        __syncthreads();
    }
    // D: row(patch) = q*4+r (+16mt+32wm+64pm), col(oc) = low (+16nt+32wn+64nb)
#pragma unroll
    for (int mt = 0; mt < 2; ++mt) {
        int patch = pm * 64 + wm * 32 + mt * 16 + q * 4;
#pragma unroll
        for (int nt = 0; nt < 2; ++nt) {
            int oc = nb * 64 + wn * 32 + nt * 16 + low;
#pragma unroll
            for (int r = 0; r < 4; ++r)
                part[((long)kc * 1024 + patch + r) * 512 + oc] = acc[mt][nt][r];
        }
    }
}

// reduce partials, add bias, pack k -> [b][h][key][c], v -> [b][h][c][key] (f16)
__global__ __launch_bounds__(256) void k_kv_fin(const float* __restrict__ part,
                                                const float* __restrict__ bk,
                                                const float* __restrict__ bv,
                                                short* __restrict__ kp,
                                                short* __restrict__ vp) {
    int idx = blockIdx.x * 256 + threadIdx.x;   // 524288 = 1024patch * 512oc
    int oc = idx & 511, patch = idx >> 9;
    float s = 0.f;
#pragma unroll
    for (int kc = 0; kc < 8; ++kc) s += part[(long)kc * 524288 + idx];
    int b = patch >> 8, key = patch & 255;
    if (oc < 256) {
        s += bk[oc];
        kp[(((long)(b * 8 + (oc & 7)) * 256) + key) * 32 + (oc >> 3)] = f2h(s);
    } else {
        int o = oc - 256;
        s += bv[o];
        vp[(((long)(b * 8 + (o & 7)) * 32) + (o >> 3)) * 256 + key] = f2h(s);
    }
}

// ---------------- Q conv (1x1) as GEMM (no staging LDS, D[px][oc]) -------
// A-frag = xn[px][c], B-frag = wqp[oc][c] (L2-hot). grid 1024; 4 waves.
// q stored as [b][h 8][px 16384][c 32] f16, PRE-SCALED by log2(e) (r16 note).
__global__ __launch_bounds__(256) void k_q_gemm(const short* __restrict__ xn,
                                                const short* __restrict__ wqp,
                                                const float* __restrict__ bq,
                                                short* __restrict__ qp) {
    __shared__ short Tb[64 * 256];  // 32 KB
    int bi = blockIdx.x;            // 1024 = 4b * 256 tiles
    int b = bi >> 8, tile = bi & 255;
    long px0 = (long)tile * 64;
    int t = threadIdx.x, l = t & 63, w = t >> 6;
    int low = l & 15, q = l >> 4;

    const short* xb = xn + (((long)(b << 14)) + px0) * 256;

    float bqv[4];
#pragma unroll
    for (int nt = 0; nt < 4; ++nt) bqv[nt] = bq[w * 64 + nt * 16 + low];

    f32x4 acc[4][4];   // [mt: px][nt: oc]
#pragma unroll
    for (int mt = 0; mt < 4; ++mt)
#pragma unroll
        for (int nt = 0; nt < 4; ++nt) acc[mt][nt] = (f32x4){0.f, 0.f, 0.f, 0.f};

#pragma unroll
    for (int kstep = 0; kstep < 8; ++kstep) {
        short8 af[4], bf[4];
#pragma unroll
        for (int mt = 0; mt < 4; ++mt)
            af[mt] = *(const short8*)(xb + (mt * 16 + low) * 256 + kstep * 32 + q * 8);
#pragma unroll
        for (int nt = 0; nt < 4; ++nt)
            bf[nt] = *(const short8*)(wqp + (w * 64 + nt * 16 + low) * 256 + kstep * 32 + q * 8);
#pragma unroll
        for (int mt = 0; mt < 4; ++mt)
#pragma unroll
            for (int nt = 0; nt < 4; ++nt)
                acc[mt][nt] = mfma_k32(af[mt], bf[nt], acc[mt][nt]);
    }
    // D: px = mt*16 + q*4 + r, oc = w*64 + nt*16 + low.
    // Tb[px][h 8][c 32] pitch 256 shorts; 16B-granule index XOR (px&7).
    const float LOG2E = 1.44269504088896f;
#pragma unroll
    for (int mt = 0; mt < 4; ++mt)
#pragma unroll
        for (int nt = 0; nt < 4; ++nt) {
            int oc = w * 64 + nt * 16 + low;
            int h8 = oc & 7, cc = oc >> 3;
            int gi = h8 * 4 + (cc >> 3);          // 16B granule 0..31 within row
#pragma unroll
            for (int r = 0; r < 4; ++r) {
                int px = mt * 16 + q * 4 + r;
                Tb[px * 256 + ((gi ^ (px & 7)) * 8) + (cc & 7)] =
                    f2h((acc[mt][nt][r] + bqv[nt]) * LOG2E);
            }
        }
    __syncthreads();
#pragma unroll
    for (int i = 0; i < 8; ++i) {
        int g = i * 256 + t;            // 2048 chunks of 16B
        int pxl = g >> 5, g16 = g & 31; // g16 = hh*4 + oct
        int hh = g16 >> 2, oct = g16 & 3;
        short8 v = *(const short8*)(Tb + pxl * 256 + ((g16 ^ (pxl & 7)) * 8));
        *(short8*)(qp + (((long)(b * 8 + hh) * 16384) + px0 + pxl) * 32 + oct * 8) = v;
    }
}

// ---------------- fused attention (v13: pitch-40 K rows, exp2, ones-row) ----
// grid 2048 = 4b * 8h * 64 tiles of 256px; block 256 thr = 4 waves x 64 px.
// Kl pitch 40 shorts (80B rows): bank base (20*low+4q)%32 -> ~2-way (free)
// vs pitch-32's 8-way. Two-pass QK^T; logits log2e-scaled -> raw v_exp_f32;
// ones-row MFMA denominator; LDS bases hoisted to compile-time offsets.
__global__ __launch_bounds__(256) void k_attn(const short* __restrict__ qp,
                                              const short* __restrict__ kp,
                                              const short* __restrict__ vp,
                                              float* __restrict__ out) {
    __shared__ short Kl[256 * 40];   // 20 KB
    __shared__ short Vl[32 * 264];   // 16.9 KB
    int bi = blockIdx.x;
    int tile = bi & 63, h = (bi >> 6) & 7, b = bi >> 9;
    int bh = b * 8 + h;
    long px0 = (long)tile * 256;
    int t = threadIdx.x, l = t & 63, w = t >> 6;
    int low = l & 15, q = l >> 4;

    const short* kbase = kp + (long)bh * 8192;    // [key 256][c 32]
    const short* vbase = vp + (long)bh * 8192;    // [c 32][key 256]
    const short* qbase = qp + (long)bh * 16384 * 32;  // [px][c 32]

    // stage K -> LDS, pitch 40 shorts (1024 granules of 16B)
#pragma unroll
    for (int i = 0; i < 4; ++i) {
        int g = i * 256 + t;
        *(short8*)(Kl + (g >> 2) * 40 + (g & 3) * 8) = *(const short8*)(kbase + g * 8);
    }
    // stage V -> LDS (pitch 264)
#pragma unroll
    for (int i = 0; i < 4; ++i) {
        int g = i * 256 + t;
        int c = g >> 5, k8 = g & 31;
        *(short8*)(Vl + c * 264 + k8 * 8) = *(const short8*)(vbase + c * 256 + k8 * 8);
    }
    __syncthreads();

    const short* kA = Kl + low * 40 + q * 8;   // + mt*640 (imm offset)
    const short* vA = Vl + low * 264 + q * 4;  // + ct*4224 + kc*16 (imm offset)
    const sh4 sone = {0x3C00, 0x3C00, 0x3C00, 0x3C00};
    const half4 vones = __builtin_bit_cast(half4, sone);

#pragma unroll 1
    for (int nt = 0; nt < 4; ++nt) {
        long px = px0 + w * 64 + nt * 16 + low;
        // q B-frag: 16B contiguous (k = c = q*8+j); values log2e-scaled
        short8 bq2 = *(const short8*)(qbase + px * 32 + q * 8);

        // pass 1: exact row max (pairwise fmax -> v_max3-fusable)
        float m = -1e30f;
#pragma unroll
        for (int mt = 0; mt < 16; ++mt) {
            short8 ak = *(const short8*)(kA + mt * 640);
            f32x4 d = mfma_k32(ak, bq2, (f32x4){0.f, 0.f, 0.f, 0.f});
            m = fmaxf(fmaxf(d[0], d[1]), m);
            m = fmaxf(fmaxf(d[2], d[3]), m);
        }
        m = fmaxf(m, __shfl_xor(m, 16));
        m = fmaxf(m, __shfl_xor(m, 32));

        // pass 2: recompute, 2^x directly (no mul), pack P to f16
        uint2v pk[16];
#pragma unroll
        for (int mt = 0; mt < 16; ++mt) {
            short8 ak = *(const short8*)(kA + mt * 640);
            f32x4 d = mfma_k32(ak, bq2, (f32x4){0.f, 0.f, 0.f, 0.f});
            float p0 = exp2_raw(d[0] - m);
            float p1 = exp2_raw(d[1] - m);
            float p2 = exp2_raw(d[2] - m);
            float p3 = exp2_raw(d[3] - m);
            pk[mt][0] = pkrtz(p0, p1);
            pk[mt][1] = pkrtz(p2, p3);
        }

        // PV + ones-row denominator (both on the MFMA pipe)
        f32x4 o2[2], os;
        o2[0] = (f32x4){0.f, 0.f, 0.f, 0.f};
        o2[1] = (f32x4){0.f, 0.f, 0.f, 0.f};
        os    = (f32x4){0.f, 0.f, 0.f, 0.f};
        __builtin_amdgcn_s_setprio(1);
#pragma unroll
        for (int kc = 0; kc < 16; ++kc) {
            half4 pb = __builtin_bit_cast(half4, pk[kc]);
            half4 av0 = __builtin_bit_cast(half4, *(const sh4*)(vA + kc * 16));
            half4 av1 = __builtin_bit_cast(half4, *(const sh4*)(vA + 4224 + kc * 16));
            o2[0] = mfma_k16(av0, pb, o2[0]);
            o2[1] = mfma_k16(av1, pb, o2[1]);
            os    = mfma_k16(vones, pb, os);
        }
        __builtin_amdgcn_s_setprio(0);
        float inv = 1.0f / os[0];   // column sum for this lane's px

        // write out [b][c*8+h][px] fp32; D row=c=ct*16+q*4+r, col=px
#pragma unroll
        for (int ct = 0; ct < 2; ++ct)
#pragma unroll
            for (int r = 0; r < 4; ++r) {
                int c = ct * 16 + q * 4 + r;
                out[(((long)(b * 256 + c * 8 + h)) << 14) + px] = o2[ct][r] * inv;
            }
    }
}

// ---------------- launch ----------------
extern "C" void kernel_launch(void* const* d_in, const int* in_sizes, int n_in,
                              void* d_out, int out_size, void* d_ws, size_t ws_size,
                              hipStream_t stream) {
    const float* x  = (const float*)d_in[0];
    const float* Wq = (const float*)d_in[1];
    const float* bq = (const float*)d_in[2];
    const float* Wk = (const float*)d_in[3];
    const float* bk = (const float*)d_in[4];
    const float* Wv = (const float*)d_in[5];
    const float* bv = (const float*)d_in[6];
    float* out = (float*)d_out;

    char* ws = (char*)d_ws;
    const size_t OFF_XN = 0;             // 33,554,432  x NHWC f16
    const size_t OFF_Q  = 33554432;      // 33,554,432  q [b][h][px][c] f16 (log2e-scaled)
    const size_t OFF_WP = 67108864;      // 16,777,216  w_pack [512][16384] f16
    const size_t OFF_WQ = 83886080;      //    131,072  wq f16
    const size_t OFF_KP = 84017152;      //    524,288  k_pack f16
    const size_t OFF_VP = 84541440;      //    524,288  v_pack f16
    const size_t OFF_PT = 85065728;      // 16,777,216  partials fp32 [8][1024][512]
    const size_t NEEDED = 118620160;
    if (ws_size < NEEDED) return;        // fail loudly via validation

    short* xn  = (short*)(ws + OFF_XN);
    short* qp  = (short*)(ws + OFF_Q);
    short* wp  = (short*)(ws + OFF_WP);
    short* wqp = (short*)(ws + OFF_WQ);
    short* kp  = (short*)(ws + OFF_KP);
    short* vp  = (short*)(ws + OFF_VP);
    float* part= (float*)(ws + OFF_PT);

    k_pack_x <<<dim3(4096), dim3(256), 0, stream>>>(x, xn);
    k_pack_w <<<dim3(2048), dim3(256), 0, stream>>>(Wk, Wv, wp);
    k_pack_wq<<<dim3(256),  dim3(256), 0, stream>>>(Wq, wqp);
    k_kv_gemm<<<dim3(1024), dim3(256), 0, stream>>>(xn, wp, part);
    k_kv_fin <<<dim3(2048), dim3(256), 0, stream>>>(part, bk, bv, kp, vp);
    k_q_gemm <<<dim3(1024), dim3(256), 0, stream>>>(xn, wqp, bq, qp);
    k_attn   <<<dim3(2048), dim3(256), 0, stream>>>(qp, kp, vp, out);
}

// Round 18
// 146.627 us; speedup vs baseline: 1.0734x; 1.0734x over previous
//
#include <hip/hip_runtime.h>
#include <stdint.h>

// ---------------- types & helpers ----------------
typedef short sh4 __attribute__((ext_vector_type(4)));
typedef short short8 __attribute__((ext_vector_type(8)));
typedef float f32x4 __attribute__((ext_vector_type(4)));
typedef _Float16 half4 __attribute__((ext_vector_type(4)));
typedef _Float16 half8 __attribute__((ext_vector_type(8)));
typedef unsigned int uint2v __attribute__((ext_vector_type(2)));

__device__ __forceinline__ short f2h(float f) {
    _Float16 h = (_Float16)f;
    return __builtin_bit_cast(short, h);
}

__device__ __forceinline__ f32x4 mfma_k32(short8 a, short8 b, f32x4 c) {
    return __builtin_amdgcn_mfma_f32_16x16x32_f16(
        __builtin_bit_cast(half8, a), __builtin_bit_cast(half8, b), c, 0, 0, 0);
}
__device__ __forceinline__ f32x4 mfma_k16(half4 a, half4 b, f32x4 c) {
    return __builtin_amdgcn_mfma_f32_16x16x16f16(a, b, c, 0, 0, 0);
}
__device__ __forceinline__ unsigned int pkrtz(float a, float b) {
    return __builtin_bit_cast(unsigned int, __builtin_amdgcn_cvt_pkrtz(a, b));
}
__device__ __forceinline__ float exp2_raw(float x) {
    float r;
    asm("v_exp_f32 %0, %1" : "=v"(r) : "v"(x));   // 2^x, single instr
    return r;
}

// Problem constants: B=4, C=256, H=W=128 (PX=16384), inner=256, heads=8, c/head=32,
// patch=8 -> keys=256, conv K-dim = 256*64 = 16384.
// NOTE (r6/r14): exp shift must be the exact row max from the logits.
// NOTE (r9-r11): f16 logit stash -> wrong results (bisected). f32 stash is FINE
//   (r5 passed with d[16] f32 live). exp must run on f32 MFMA outputs.
// NOTE (r9 vs r10): ones-row MFMA denominator == shfl-sum (bit-identical);
//   verified passing since r16 (VALU -> MFMA shift).
// NOTE (r13 vs r18): register stash is an OCCUPANCY trade. At r13's 124-base
//   VGPR it regressed (156 total); at r16's 72-base it fits (~136) -> try.
// NOTE (r16): q is PRE-SCALED by log2(e) in k_q_gemm -> raw v_exp_f32 in attn.
// NOTE (r17): Kl pitch-40 did NOT reduce SQ_LDS_BANK_CONFLICT (6.7M->6.9M) --
//   conflict source is not the K-row pitch; pitch-32 kept (smaller LDS).
//   kv_gemm 64x64/4-per-CU retile was neutral-negative; 128x64/2-per-CU kept.

// ---------------- pack kernels: 64x64 fp32 tile transpose -> f16 ----------------
__device__ __forceinline__ void transpose64(const float* __restrict__ src,
                                            short* __restrict__ dst,
                                            int srcSlowStride, int dstRowStride) {
    __shared__ float tile[64][65];
    const int t = threadIdx.x;
#pragma unroll
    for (int i = 0; i < 16; ++i) {
        int idx = i * 256 + t;
        int fast = idx & 63, slow = idx >> 6;
        tile[slow][fast] = src[(long)slow * srcSlowStride + fast];
    }
    __syncthreads();
#pragma unroll
    for (int i = 0; i < 2; ++i) {
        int ch = i * 256 + t;
        int fast = ch >> 3, sg = ch & 7;
        short8 v;
#pragma unroll
        for (int j = 0; j < 8; ++j) v[j] = f2h(tile[sg * 8 + j][fast]);
        *(short8*)(dst + (long)fast * dstRowStride + sg * 8) = v;
    }
}

// x: [4][256][16384] fp32 (NCHW) -> xn: [4][16384][256] f16 (NHWC)
__global__ __launch_bounds__(256) void k_pack_x(const float* __restrict__ x,
                                                short* __restrict__ xn) {
    int bi = blockIdx.x;                 // 4096 = 4b * 256pxt * 4ct
    int ct = bi & 3, pxt = (bi >> 2) & 255, b = bi >> 10;
    const float* src = x + (((long)(b * 256 + ct * 64)) << 14) + (long)pxt * 64;
    short* dst = xn + (((long)(b << 14) + pxt * 64) * 256) + ct * 64;
    transpose64(src, dst, 16384, 256);
}

// Wk/Wv: [256][256][64] fp32 -> wp: [512][64][256] f16 (oc<256: k, else v), K order (dydx, c)
__global__ __launch_bounds__(256) void k_pack_w(const float* __restrict__ wk,
                                                const float* __restrict__ wv,
                                                short* __restrict__ wp) {
    int bi = blockIdx.x;                 // 2048 = 512oc * 4ct
    int ct = bi & 3, oc = bi >> 2;
    const float* base = (oc < 256) ? (wk + (long)oc * 16384) : (wv + (long)(oc - 256) * 16384);
    const float* src = base + ct * 4096; // + c0*64
    short* dst = wp + (long)oc * 16384 + ct * 64;
    transpose64(src, dst, 64, 256);
}

// Wq: [256][256] fp32 -> f16 (layout preserved: [oc][c])
__global__ __launch_bounds__(256) void k_pack_wq(const float* __restrict__ wq,
                                                 short* __restrict__ wqp) {
    int i = blockIdx.x * 256 + threadIdx.x; // grid 256 -> 65536
    wqp[i] = f2h(wq[i]);
}

// ---------------- K/V conv as GEMM (128x64 tile, 512 blocks, 2/CU) ----
// C[patch 1024][oc 512] = A[patch][k 16384] * B[k][oc]
// grid 512 = 8kc * 8pm * 8nb; block 256 thr (4 waves); Kchunk 2048 (32 x BK=64).
__global__ __launch_bounds__(256) void k_kv_gemm(const short* __restrict__ xn,
                                                 const short* __restrict__ wp,
                                                 float* __restrict__ part) {
    __shared__ short Al[128 * 64]; // rows 128B = 8 granules, swizzled
    __shared__ short Bl[64 * 64];
    int bid = blockIdx.x;                       // 512
    int wg = (bid & 7) * 64 + (bid >> 3);       // XCD-contiguous swizzle (512 = 8*64)
    int nb = wg & 7, pm = (wg >> 3) & 7, kc = wg >> 6;
    int t = threadIdx.x, l = t & 63, w = t >> 6;
    int wm = w >> 1, wn = w & 1;
    int low = l & 15, q = l >> 4;

    f32x4 acc[4][2];
#pragma unroll
    for (int mt = 0; mt < 4; ++mt)
#pragma unroll
        for (int nt = 0; nt < 2; ++nt) acc[mt][nt] = (f32x4){0.f, 0.f, 0.f, 0.f};

    for (int kk = 0; kk < 32; ++kk) {
        short8 va[4], vb[2];
#pragma unroll
        for (int i = 0; i < 4; ++i) {           // A: 1024 granules (128 rows x 8)
            int g = i * 256 + t;
            int row = g >> 3, lg = g & 7;
            int patch = pm * 128 + row;
            int kg = kc * 2048 + kk * 64 + lg * 8;
            int dydx = kg >> 8, cc = kg & 255;
            int bb = patch >> 8, pid = patch & 255;
            int ph = pid >> 4, pw = pid & 15;
            int px = (ph * 8 + (dydx >> 3)) * 128 + pw * 8 + (dydx & 7);
            va[i] = *(const short8*)(xn + ((long)(bb << 14) + px) * 256 + cc);
        }
#pragma unroll
        for (int i = 0; i < 2; ++i) {           // B: 512 granules (64 rows x 8)
            int g = i * 256 + t;
            int row = g >> 3, lg = g & 7;
            int oc = nb * 64 + row;
            int kg = kc * 2048 + kk * 64 + lg * 8;
            vb[i] = *(const short8*)(wp + (long)oc * 16384 + kg);
        }
#pragma unroll
        for (int i = 0; i < 4; ++i) {
            int g = i * 256 + t;
            int row = g >> 3, lg = g & 7;
            *(short8*)(Al + row * 64 + ((lg ^ (row & 7)) * 8)) = va[i];
        }
#pragma unroll
        for (int i = 0; i < 2; ++i) {
            int g = i * 256 + t;
            int row = g >> 3, lg = g & 7;
            *(short8*)(Bl + row * 64 + ((lg ^ (row & 7)) * 8)) = vb[i];
        }
        __syncthreads();
#pragma unroll
        for (int ks = 0; ks < 2; ++ks) {
            short8 af[4], bf[2];
#pragma unroll
            for (int mt = 0; mt < 4; ++mt) {
                int row = wm * 64 + mt * 16 + low;
                int lg = ks * 4 + q;
                af[mt] = *(const short8*)(Al + row * 64 + ((lg ^ (row & 7)) * 8));
            }
#pragma unroll
            for (int nt = 0; nt < 2; ++nt) {
                int row = wn * 32 + nt * 16 + low;
                int lg = ks * 4 + q;
                bf[nt] = *(const short8*)(Bl + row * 64 + ((lg ^ (row & 7)) * 8));
            }
#pragma unroll
            for (int mt = 0; mt < 4; ++mt)
#pragma unroll
                for (int nt = 0; nt < 2; ++nt)
                    acc[mt][nt] = mfma_k32(af[mt], bf[nt], acc[mt][nt]);
        }
        __syncthreads();
    }
    // D: row(patch) = q*4+r (+16mt+64wm+128pm), col(oc) = low (+16nt+32wn+64nb)
#pragma unroll
    for (int mt = 0; mt < 4; ++mt) {
        int patch = pm * 128 + wm * 64 + mt * 16 + q * 4;
#pragma unroll
        for (int nt = 0; nt < 2; ++nt) {
            int oc = nb * 64 + wn * 32 + nt * 16 + low;
#pragma unroll
            for (int r = 0; r < 4; ++r)
                part[((long)kc * 1024 + patch + r) * 512 + oc] = acc[mt][nt][r];
        }
    }
}

// reduce partials, add bias, pack k -> [b][h][key][c], v -> [b][h][c][key] (f16)
__global__ __launch_bounds__(256) void k_kv_fin(const float* __restrict__ part,
                                                const float* __restrict__ bk,
                                                const float* __restrict__ bv,
                                                short* __restrict__ kp,
                                                short* __restrict__ vp) {
    int idx = blockIdx.x * 256 + threadIdx.x;   // 524288 = 1024patch * 512oc
    int oc = idx & 511, patch = idx >> 9;
    float s = 0.f;
#pragma unroll
    for (int kc = 0; kc < 8; ++kc) s += part[(long)kc * 524288 + idx];
    int b = patch >> 8, key = patch & 255;
    if (oc < 256) {
        s += bk[oc];
        kp[(((long)(b * 8 + (oc & 7)) * 256) + key) * 32 + (oc >> 3)] = f2h(s);
    } else {
        int o = oc - 256;
        s += bv[o];
        vp[(((long)(b * 8 + (o & 7)) * 32) + (o >> 3)) * 256 + key] = f2h(s);
    }
}

// ---------------- Q conv (1x1) as GEMM (no staging LDS, D[px][oc]) -------
// A-frag = xn[px][c], B-frag = wqp[oc][c] (L2-hot). grid 1024; 4 waves.
// q stored as [b][h 8][px 16384][c 32] f16, PRE-SCALED by log2(e) (r16 note).
__global__ __launch_bounds__(256) void k_q_gemm(const short* __restrict__ xn,
                                                const short* __restrict__ wqp,
                                                const float* __restrict__ bq,
                                                short* __restrict__ qp) {
    __shared__ short Tb[64 * 256];  // 32 KB
    int bi = blockIdx.x;            // 1024 = 4b * 256 tiles
    int b = bi >> 8, tile = bi & 255;
    long px0 = (long)tile * 64;
    int t = threadIdx.x, l = t & 63, w = t >> 6;
    int low = l & 15, q = l >> 4;

    const short* xb = xn + (((long)(b << 14)) + px0) * 256;

    float bqv[4];
#pragma unroll
    for (int nt = 0; nt < 4; ++nt) bqv[nt] = bq[w * 64 + nt * 16 + low];

    f32x4 acc[4][4];   // [mt: px][nt: oc]
#pragma unroll
    for (int mt = 0; mt < 4; ++mt)
#pragma unroll
        for (int nt = 0; nt < 4; ++nt) acc[mt][nt] = (f32x4){0.f, 0.f, 0.f, 0.f};

#pragma unroll
    for (int kstep = 0; kstep < 8; ++kstep) {
        short8 af[4], bf[4];
#pragma unroll
        for (int mt = 0; mt < 4; ++mt)
            af[mt] = *(const short8*)(xb + (mt * 16 + low) * 256 + kstep * 32 + q * 8);
#pragma unroll
        for (int nt = 0; nt < 4; ++nt)
            bf[nt] = *(const short8*)(wqp + (w * 64 + nt * 16 + low) * 256 + kstep * 32 + q * 8);
#pragma unroll
        for (int mt = 0; mt < 4; ++mt)
#pragma unroll
            for (int nt = 0; nt < 4; ++nt)
                acc[mt][nt] = mfma_k32(af[mt], bf[nt], acc[mt][nt]);
    }
    // D: px = mt*16 + q*4 + r, oc = w*64 + nt*16 + low.
    // Tb[px][h 8][c 32] pitch 256 shorts; 16B-granule index XOR (px&7).
    const float LOG2E = 1.44269504088896f;
#pragma unroll
    for (int mt = 0; mt < 4; ++mt)
#pragma unroll
        for (int nt = 0; nt < 4; ++nt) {
            int oc = w * 64 + nt * 16 + low;
            int h8 = oc & 7, cc = oc >> 3;
            int gi = h8 * 4 + (cc >> 3);          // 16B granule 0..31 within row
#pragma unroll
            for (int r = 0; r < 4; ++r) {
                int px = mt * 16 + q * 4 + r;
                Tb[px * 256 + ((gi ^ (px & 7)) * 8) + (cc & 7)] =
                    f2h((acc[mt][nt][r] + bqv[nt]) * LOG2E);
            }
        }
    __syncthreads();
#pragma unroll
    for (int i = 0; i < 8; ++i) {
        int g = i * 256 + t;            // 2048 chunks of 16B
        int pxl = g >> 5, g16 = g & 31; // g16 = hh*4 + oct
        int hh = g16 >> 2, oct = g16 & 3;
        short8 v = *(const short8*)(Tb + pxl * 256 + ((g16 ^ (pxl & 7)) * 8));
        *(short8*)(qp + (((long)(b * 8 + hh) * 16384) + px0 + pxl) * 32 + oct * 8) = v;
    }
}

// ---------------- fused attention (v14: single-pass QK^T, f32 stash) ----
// grid 2048 = 4b * 8h * 64 tiles of 256px; block 256 thr = 4 waves x 64 px.
// Single QK^T pass with f32 dd[16] stash (r5-verified arithmetic): removes
// the 16-MFMA recompute pass + 16 LDS reads per nt. Affordable now that the
// base VGPR is 72 (r16). exp2 on f32 outputs; ones-row MFMA denominator.
__global__ __launch_bounds__(256) void k_attn(const short* __restrict__ qp,
                                              const short* __restrict__ kp,
                                              const short* __restrict__ vp,
                                              float* __restrict__ out) {
    __shared__ short Kl[256 * 32];   // 16 KB, straight copy of kp tile
    __shared__ short Vl[32 * 264];   // 16.9 KB
    int bi = blockIdx.x;
    int tile = bi & 63, h = (bi >> 6) & 7, b = bi >> 9;
    int bh = b * 8 + h;
    long px0 = (long)tile * 256;
    int t = threadIdx.x, l = t & 63, w = t >> 6;
    int low = l & 15, q = l >> 4;

    const short* kbase = kp + (long)bh * 8192;    // [key 256][c 32]
    const short* vbase = vp + (long)bh * 8192;    // [c 32][key 256]
    const short* qbase = qp + (long)bh * 16384 * 32;  // [px][c 32]

    // stage K -> LDS (straight 16KB copy, coalesced)
#pragma unroll
    for (int i = 0; i < 4; ++i) {
        int g = i * 256 + t;
        *(short8*)(Kl + g * 8) = *(const short8*)(kbase + g * 8);
    }
    // stage V -> LDS (pitch 264)
#pragma unroll
    for (int i = 0; i < 4; ++i) {
        int g = i * 256 + t;
        int c = g >> 5, k8 = g & 31;
        *(short8*)(Vl + c * 264 + k8 * 8) = *(const short8*)(vbase + c * 256 + k8 * 8);
    }
    __syncthreads();

    const short* kA = Kl + low * 32 + q * 8;   // + mt*512 (imm offset)
    const short* vA = Vl + low * 264 + q * 4;  // + ct*4224 + kc*16 (imm offset)
    const sh4 sone = {0x3C00, 0x3C00, 0x3C00, 0x3C00};
    const half4 vones = __builtin_bit_cast(half4, sone);

#pragma unroll 1
    for (int nt = 0; nt < 4; ++nt) {
        long px = px0 + w * 64 + nt * 16 + low;
        // q B-frag: 16B contiguous (k = c = q*8+j); values log2e-scaled
        short8 bq2 = *(const short8*)(qbase + px * 32 + q * 8);

        // single QK^T pass: f32 stash + folded row max (r5-verified)
        f32x4 dd[16];
        float m = -1e30f;
#pragma unroll
        for (int mt = 0; mt < 16; ++mt) {
            short8 ak = *(const short8*)(kA + mt * 512);
            dd[mt] = mfma_k32(ak, bq2, (f32x4){0.f, 0.f, 0.f, 0.f});
            m = fmaxf(fmaxf(dd[mt][0], dd[mt][1]), m);
            m = fmaxf(fmaxf(dd[mt][2], dd[mt][3]), m);
        }
        m = fmaxf(m, __shfl_xor(m, 16));
        m = fmaxf(m, __shfl_xor(m, 32));

        // exp2 from f32 stash, pack P to f16
        uint2v pk[16];
#pragma unroll
        for (int mt = 0; mt < 16; ++mt) {
            float p0 = exp2_raw(dd[mt][0] - m);
            float p1 = exp2_raw(dd[mt][1] - m);
            float p2 = exp2_raw(dd[mt][2] - m);
            float p3 = exp2_raw(dd[mt][3] - m);
            pk[mt][0] = pkrtz(p0, p1);
            pk[mt][1] = pkrtz(p2, p3);
        }

        // PV + ones-row denominator (both on the MFMA pipe)
        f32x4 o2[2], os;
        o2[0] = (f32x4){0.f, 0.f, 0.f, 0.f};
        o2[1] = (f32x4){0.f, 0.f, 0.f, 0.f};
        os    = (f32x4){0.f, 0.f, 0.f, 0.f};
        __builtin_amdgcn_s_setprio(1);
#pragma unroll
        for (int kc = 0; kc < 16; ++kc) {
            half4 pb = __builtin_bit_cast(half4, pk[kc]);
            half4 av0 = __builtin_bit_cast(half4, *(const sh4*)(vA + kc * 16));
            half4 av1 = __builtin_bit_cast(half4, *(const sh4*)(vA + 4224 + kc * 16));
            o2[0] = mfma_k16(av0, pb, o2[0]);
            o2[1] = mfma_k16(av1, pb, o2[1]);
            os    = mfma_k16(vones, pb, os);
        }
        __builtin_amdgcn_s_setprio(0);
        float inv = 1.0f / os[0];   // column sum for this lane's px

        // write out [b][c*8+h][px] fp32; D row=c=ct*16+q*4+r, col=px
#pragma unroll
        for (int ct = 0; ct < 2; ++ct)
#pragma unroll
            for (int r = 0; r < 4; ++r) {
                int c = ct * 16 + q * 4 + r;
                out[(((long)(b * 256 + c * 8 + h)) << 14) + px] = o2[ct][r] * inv;
            }
    }
}

// ---------------- launch ----------------
extern "C" void kernel_launch(void* const* d_in, const int* in_sizes, int n_in,
                              void* d_out, int out_size, void* d_ws, size_t ws_size,
                              hipStream_t stream) {
    const float* x  = (const float*)d_in[0];
    const float* Wq = (const float*)d_in[1];
    const float* bq = (const float*)d_in[2];
    const float* Wk = (const float*)d_in[3];
    const float* bk = (const float*)d_in[4];
    const float* Wv = (const float*)d_in[5];
    const float* bv = (const float*)d_in[6];
    float* out = (float*)d_out;

    char* ws = (char*)d_ws;
    const size_t OFF_XN = 0;             // 33,554,432  x NHWC f16
    const size_t OFF_Q  = 33554432;      // 33,554,432  q [b][h][px][c] f16 (log2e-scaled)
    const size_t OFF_WP = 67108864;      // 16,777,216  w_pack [512][16384] f16
    const size_t OFF_WQ = 83886080;      //    131,072  wq f16
    const size_t OFF_KP = 84017152;      //    524,288  k_pack f16
    const size_t OFF_VP = 84541440;      //    524,288  v_pack f16
    const size_t OFF_PT = 85065728;      // 16,777,216  partials fp32 [8][1024][512]
    const size_t NEEDED = 118620160;
    if (ws_size < NEEDED) return;        // fail loudly via validation

    short* xn  = (short*)(ws + OFF_XN);
    short* qp  = (short*)(ws + OFF_Q);
    short* wp  = (short*)(ws + OFF_WP);
    short* wqp = (short*)(ws + OFF_WQ);
    short* kp  = (short*)(ws + OFF_KP);
    short* vp  = (short*)(ws + OFF_VP);
    float* part= (float*)(ws + OFF_PT);

    k_pack_x <<<dim3(4096), dim3(256), 0, stream>>>(x, xn);
    k_pack_w <<<dim3(2048), dim3(256), 0, stream>>>(Wk, Wv, wp);
    k_pack_wq<<<dim3(256),  dim3(256), 0, stream>>>(Wq, wqp);
    k_kv_gemm<<<dim3(512),  dim3(256), 0, stream>>>(xn, wp, part);
    k_kv_fin <<<dim3(2048), dim3(256), 0, stream>>>(part, bk, bv, kp, vp);
    k_q_gemm <<<dim3(1024), dim3(256), 0, stream>>>(xn, wqp, bq, qp);
    k_attn   <<<dim3(2048), dim3(256), 0, stream>>>(qp, kp, vp, out);
}

// Round 19
// 146.502 us; speedup vs baseline: 1.0743x; 1.0009x over previous
//
#include <hip/hip_runtime.h>
#include <stdint.h>

// ---------------- types & helpers ----------------
typedef short sh4 __attribute__((ext_vector_type(4)));
typedef short short8 __attribute__((ext_vector_type(8)));
typedef float f32x4 __attribute__((ext_vector_type(4)));
typedef _Float16 half4 __attribute__((ext_vector_type(4)));
typedef _Float16 half8 __attribute__((ext_vector_type(8)));
typedef unsigned int uint2v __attribute__((ext_vector_type(2)));

__device__ __forceinline__ short f2h(float f) {
    _Float16 h = (_Float16)f;
    return __builtin_bit_cast(short, h);
}

__device__ __forceinline__ f32x4 mfma_k32(short8 a, short8 b, f32x4 c) {
    return __builtin_amdgcn_mfma_f32_16x16x32_f16(
        __builtin_bit_cast(half8, a), __builtin_bit_cast(half8, b), c, 0, 0, 0);
}
__device__ __forceinline__ f32x4 mfma_k16(half4 a, half4 b, f32x4 c) {
    return __builtin_amdgcn_mfma_f32_16x16x16f16(a, b, c, 0, 0, 0);
}
__device__ __forceinline__ unsigned int pkrtz(float a, float b) {
    return __builtin_bit_cast(unsigned int, __builtin_amdgcn_cvt_pkrtz(a, b));
}
__device__ __forceinline__ float exp2_raw(float x) {
    float r;
    asm("v_exp_f32 %0, %1" : "=v"(r) : "v"(x));   // 2^x, single instr
    return r;
}

// Problem constants: B=4, C=256, H=W=128 (PX=16384), inner=256, heads=8, c/head=32,
// patch=8 -> keys=256, conv K-dim = 256*64 = 16384.
// NOTE (r6/r14): exp shift must be the exact row max from the logits.
// NOTE (r9-r11): f16 logit stash -> wrong results (bisected). f32 stash is FINE
//   (r5/r18 passed). exp must run on f32 MFMA outputs.
// NOTE (r9 vs r10): ones-row MFMA denominator == shfl-sum (bit-identical);
//   verified passing since r16.
// NOTE (r16): q is PRE-SCALED by log2(e) in k_q_gemm -> raw v_exp_f32 in attn.
// NOTE (r17): Kl pitch-40 did NOT reduce bank conflicts; pitch-32 kept.
//   kv_gemm 64x64/4-per-CU retile neutral-negative; 128x64/2-per-CU kept.
// NOTE (r19): kv_gemm kk-loop restructured as kk4 x unrolled-j4: dydx (and thus
//   the px gather base) is constant within a kk4 group (j*64+lg*8 <= 248 < 256),
//   so A/B addresses hoist and j folds into load imm offsets (+128B*j).

// ---------------- pack kernels: 64x64 fp32 tile transpose -> f16 ----------------
__device__ __forceinline__ void transpose64(const float* __restrict__ src,
                                            short* __restrict__ dst,
                                            int srcSlowStride, int dstRowStride) {
    __shared__ float tile[64][65];
    const int t = threadIdx.x;
#pragma unroll
    for (int i = 0; i < 16; ++i) {
        int idx = i * 256 + t;
        int fast = idx & 63, slow = idx >> 6;
        tile[slow][fast] = src[(long)slow * srcSlowStride + fast];
    }
    __syncthreads();
#pragma unroll
    for (int i = 0; i < 2; ++i) {
        int ch = i * 256 + t;
        int fast = ch >> 3, sg = ch & 7;
        short8 v;
#pragma unroll
        for (int j = 0; j < 8; ++j) v[j] = f2h(tile[sg * 8 + j][fast]);
        *(short8*)(dst + (long)fast * dstRowStride + sg * 8) = v;
    }
}

// x: [4][256][16384] fp32 (NCHW) -> xn: [4][16384][256] f16 (NHWC)
__global__ __launch_bounds__(256) void k_pack_x(const float* __restrict__ x,
                                                short* __restrict__ xn) {
    int bi = blockIdx.x;                 // 4096 = 4b * 256pxt * 4ct
    int ct = bi & 3, pxt = (bi >> 2) & 255, b = bi >> 10;
    const float* src = x + (((long)(b * 256 + ct * 64)) << 14) + (long)pxt * 64;
    short* dst = xn + (((long)(b << 14) + pxt * 64) * 256) + ct * 64;
    transpose64(src, dst, 16384, 256);
}

// Wk/Wv: [256][256][64] fp32 -> wp: [512][64][256] f16 (oc<256: k, else v), K order (dydx, c)
__global__ __launch_bounds__(256) void k_pack_w(const float* __restrict__ wk,
                                                const float* __restrict__ wv,
                                                short* __restrict__ wp) {
    int bi = blockIdx.x;                 // 2048 = 512oc * 4ct
    int ct = bi & 3, oc = bi >> 2;
    const float* base = (oc < 256) ? (wk + (long)oc * 16384) : (wv + (long)(oc - 256) * 16384);
    const float* src = base + ct * 4096; // + c0*64
    short* dst = wp + (long)oc * 16384 + ct * 64;
    transpose64(src, dst, 64, 256);
}

// Wq: [256][256] fp32 -> f16 (layout preserved: [oc][c])
__global__ __launch_bounds__(256) void k_pack_wq(const float* __restrict__ wq,
                                                 short* __restrict__ wqp) {
    int i = blockIdx.x * 256 + threadIdx.x; // grid 256 -> 65536
    wqp[i] = f2h(wq[i]);
}

// ---------------- K/V conv as GEMM (128x64 tile, 512 blocks, 2/CU) ----
// C[patch 1024][oc 512] = A[patch][k 16384] * B[k][oc]
// grid 512 = 8kc * 8pm * 8nb; block 256 thr (4 waves); Kchunk 2048.
// kk-loop: 8 outer kk4 (addresses hoisted) x 4 unrolled j (imm offsets).
__global__ __launch_bounds__(256) void k_kv_gemm(const short* __restrict__ xn,
                                                 const short* __restrict__ wp,
                                                 float* __restrict__ part) {
    __shared__ short Al[128 * 64]; // rows 128B = 8 granules, swizzled
    __shared__ short Bl[64 * 64];
    int bid = blockIdx.x;                       // 512
    int wg = (bid & 7) * 64 + (bid >> 3);       // XCD-contiguous swizzle (512 = 8*64)
    int nb = wg & 7, pm = (wg >> 3) & 7, kc = wg >> 6;
    int t = threadIdx.x, l = t & 63, w = t >> 6;
    int wm = w >> 1, wn = w & 1;
    int low = l & 15, q = l >> 4;

    // LDS staging addresses (loop-invariant)
    short* lda[4];
    short* ldb[2];
#pragma unroll
    for (int i = 0; i < 4; ++i) {
        int g = i * 256 + t;
        int row = g >> 3, lg = g & 7;
        lda[i] = Al + row * 64 + ((lg ^ (row & 7)) * 8);
    }
#pragma unroll
    for (int i = 0; i < 2; ++i) {
        int g = i * 256 + t;
        int row = g >> 3, lg = g & 7;
        ldb[i] = Bl + row * 64 + ((lg ^ (row & 7)) * 8);
    }

    f32x4 acc[4][2];
#pragma unroll
    for (int mt = 0; mt < 4; ++mt)
#pragma unroll
        for (int nt = 0; nt < 2; ++nt) acc[mt][nt] = (f32x4){0.f, 0.f, 0.f, 0.f};

#pragma unroll 1
    for (int kk4 = 0; kk4 < 8; ++kk4) {
        // A/B base pointers for this kk4 (dydx = kc*8 + kk4 constant; j adds 64 shorts)
        const short* apt[4];
        const short* bpt[2];
        int dydx = kc * 8 + kk4;
#pragma unroll
        for (int i = 0; i < 4; ++i) {
            int g = i * 256 + t;
            int row = g >> 3, lg = g & 7;
            int patch = pm * 128 + row;
            int bb = patch >> 8, pid = patch & 255;
            int ph = pid >> 4, pw = pid & 15;
            int px = (ph * 8 + (dydx >> 3)) * 128 + pw * 8 + (dydx & 7);
            apt[i] = xn + ((long)(bb << 14) + px) * 256 + lg * 8;
        }
#pragma unroll
        for (int i = 0; i < 2; ++i) {
            int g = i * 256 + t;
            int row = g >> 3, lg = g & 7;
            int oc = nb * 64 + row;
            bpt[i] = wp + (long)oc * 16384 + kc * 2048 + kk4 * 256 + lg * 8;
        }
#pragma unroll
        for (int j = 0; j < 4; ++j) {
            short8 va[4], vb[2];
#pragma unroll
            for (int i = 0; i < 4; ++i) va[i] = *(const short8*)(apt[i] + j * 64);
#pragma unroll
            for (int i = 0; i < 2; ++i) vb[i] = *(const short8*)(bpt[i] + j * 64);
#pragma unroll
            for (int i = 0; i < 4; ++i) *(short8*)lda[i] = va[i];
#pragma unroll
            for (int i = 0; i < 2; ++i) *(short8*)ldb[i] = vb[i];
            __syncthreads();
#pragma unroll
            for (int ks = 0; ks < 2; ++ks) {
                short8 af[4], bf[2];
#pragma unroll
                for (int mt = 0; mt < 4; ++mt) {
                    int row = wm * 64 + mt * 16 + low;
                    int lg = ks * 4 + q;
                    af[mt] = *(const short8*)(Al + row * 64 + ((lg ^ (row & 7)) * 8));
                }
#pragma unroll
                for (int nt = 0; nt < 2; ++nt) {
                    int row = wn * 32 + nt * 16 + low;
                    int lg = ks * 4 + q;
                    bf[nt] = *(const short8*)(Bl + row * 64 + ((lg ^ (row & 7)) * 8));
                }
#pragma unroll
                for (int mt = 0; mt < 4; ++mt)
#pragma unroll
                    for (int nt = 0; nt < 2; ++nt)
                        acc[mt][nt] = mfma_k32(af[mt], bf[nt], acc[mt][nt]);
            }
            __syncthreads();
        }
    }
    // D: row(patch) = q*4+r (+16mt+64wm+128pm), col(oc) = low (+16nt+32wn+64nb)
#pragma unroll
    for (int mt = 0; mt < 4; ++mt) {
        int patch = pm * 128 + wm * 64 + mt * 16 + q * 4;
#pragma unroll
        for (int nt = 0; nt < 2; ++nt) {
            int oc = nb * 64 + wn * 32 + nt * 16 + low;
#pragma unroll
            for (int r = 0; r < 4; ++r)
                part[((long)kc * 1024 + patch + r) * 512 + oc] = acc[mt][nt][r];
        }
    }
}

// reduce partials, add bias, pack k -> [b][h][key][c], v -> [b][h][c][key] (f16)
__global__ __launch_bounds__(256) void k_kv_fin(const float* __restrict__ part,
                                                const float* __restrict__ bk,
                                                const float* __restrict__ bv,
                                                short* __restrict__ kp,
                                                short* __restrict__ vp) {
    int idx = blockIdx.x * 256 + threadIdx.x;   // 524288 = 1024patch * 512oc
    int oc = idx & 511, patch = idx >> 9;
    float s = 0.f;
#pragma unroll
    for (int kc = 0; kc < 8; ++kc) s += part[(long)kc * 524288 + idx];
    int b = patch >> 8, key = patch & 255;
    if (oc < 256) {
        s += bk[oc];
        kp[(((long)(b * 8 + (oc & 7)) * 256) + key) * 32 + (oc >> 3)] = f2h(s);
    } else {
        int o = oc - 256;
        s += bv[o];
        vp[(((long)(b * 8 + (o & 7)) * 32) + (o >> 3)) * 256 + key] = f2h(s);
    }
}

// ---------------- Q conv (1x1) as GEMM (no staging LDS, D[px][oc]) -------
// A-frag = xn[px][c], B-frag = wqp[oc][c] (L2-hot). grid 1024; 4 waves.
// q stored as [b][h 8][px 16384][c 32] f16, PRE-SCALED by log2(e) (r16 note).
__global__ __launch_bounds__(256) void k_q_gemm(const short* __restrict__ xn,
                                                const short* __restrict__ wqp,
                                                const float* __restrict__ bq,
                                                short* __restrict__ qp) {
    __shared__ short Tb[64 * 256];  // 32 KB
    int bi = blockIdx.x;            // 1024 = 4b * 256 tiles
    int b = bi >> 8, tile = bi & 255;
    long px0 = (long)tile * 64;
    int t = threadIdx.x, l = t & 63, w = t >> 6;
    int low = l & 15, q = l >> 4;

    const short* xb = xn + (((long)(b << 14)) + px0) * 256;

    float bqv[4];
#pragma unroll
    for (int nt = 0; nt < 4; ++nt) bqv[nt] = bq[w * 64 + nt * 16 + low];

    f32x4 acc[4][4];   // [mt: px][nt: oc]
#pragma unroll
    for (int mt = 0; mt < 4; ++mt)
#pragma unroll
        for (int nt = 0; nt < 4; ++nt) acc[mt][nt] = (f32x4){0.f, 0.f, 0.f, 0.f};

#pragma unroll
    for (int kstep = 0; kstep < 8; ++kstep) {
        short8 af[4], bf[4];
#pragma unroll
        for (int mt = 0; mt < 4; ++mt)
            af[mt] = *(const short8*)(xb + (mt * 16 + low) * 256 + kstep * 32 + q * 8);
#pragma unroll
        for (int nt = 0; nt < 4; ++nt)
            bf[nt] = *(const short8*)(wqp + (w * 64 + nt * 16 + low) * 256 + kstep * 32 + q * 8);
#pragma unroll
        for (int mt = 0; mt < 4; ++mt)
#pragma unroll
            for (int nt = 0; nt < 4; ++nt)
                acc[mt][nt] = mfma_k32(af[mt], bf[nt], acc[mt][nt]);
    }
    // D: px = mt*16 + q*4 + r, oc = w*64 + nt*16 + low.
    // Tb[px][h 8][c 32] pitch 256 shorts; 16B-granule index XOR (px&7).
    const float LOG2E = 1.44269504088896f;
#pragma unroll
    for (int mt = 0; mt < 4; ++mt)
#pragma unroll
        for (int nt = 0; nt < 4; ++nt) {
            int oc = w * 64 + nt * 16 + low;
            int h8 = oc & 7, cc = oc >> 3;
            int gi = h8 * 4 + (cc >> 3);          // 16B granule 0..31 within row
#pragma unroll
            for (int r = 0; r < 4; ++r) {
                int px = mt * 16 + q * 4 + r;
                Tb[px * 256 + ((gi ^ (px & 7)) * 8) + (cc & 7)] =
                    f2h((acc[mt][nt][r] + bqv[nt]) * LOG2E);
            }
        }
    __syncthreads();
#pragma unroll
    for (int i = 0; i < 8; ++i) {
        int g = i * 256 + t;            // 2048 chunks of 16B
        int pxl = g >> 5, g16 = g & 31; // g16 = hh*4 + oct
        int hh = g16 >> 2, oct = g16 & 3;
        short8 v = *(const short8*)(Tb + pxl * 256 + ((g16 ^ (pxl & 7)) * 8));
        *(short8*)(qp + (((long)(b * 8 + hh) * 16384) + px0 + pxl) * 32 + oct * 8) = v;
    }
}

// ---------------- fused attention (v14: single-pass QK^T, f32 stash) ----
// grid 2048 = 4b * 8h * 64 tiles of 256px; block 256 thr = 4 waves x 64 px.
// Single QK^T pass with f32 dd[16] stash (r5/r18-verified); exp2 on f32
// outputs; ones-row MFMA denominator; setprio around PV.
__global__ __launch_bounds__(256) void k_attn(const short* __restrict__ qp,
                                              const short* __restrict__ kp,
                                              const short* __restrict__ vp,
                                              float* __restrict__ out) {
    __shared__ short Kl[256 * 32];   // 16 KB, straight copy of kp tile
    __shared__ short Vl[32 * 264];   // 16.9 KB
    int bi = blockIdx.x;
    int tile = bi & 63, h = (bi >> 6) & 7, b = bi >> 9;
    int bh = b * 8 + h;
    long px0 = (long)tile * 256;
    int t = threadIdx.x, l = t & 63, w = t >> 6;
    int low = l & 15, q = l >> 4;

    const short* kbase = kp + (long)bh * 8192;    // [key 256][c 32]
    const short* vbase = vp + (long)bh * 8192;    // [c 32][key 256]
    const short* qbase = qp + (long)bh * 16384 * 32;  // [px][c 32]

    // stage K -> LDS (straight 16KB copy, coalesced)
#pragma unroll
    for (int i = 0; i < 4; ++i) {
        int g = i * 256 + t;
        *(short8*)(Kl + g * 8) = *(const short8*)(kbase + g * 8);
    }
    // stage V -> LDS (pitch 264)
#pragma unroll
    for (int i = 0; i < 4; ++i) {
        int g = i * 256 + t;
        int c = g >> 5, k8 = g & 31;
        *(short8*)(Vl + c * 264 + k8 * 8) = *(const short8*)(vbase + c * 256 + k8 * 8);
    }
    __syncthreads();

    const short* kA = Kl + low * 32 + q * 8;   // + mt*512 (imm offset)
    const short* vA = Vl + low * 264 + q * 4;  // + ct*4224 + kc*16 (imm offset)
    const sh4 sone = {0x3C00, 0x3C00, 0x3C00, 0x3C00};
    const half4 vones = __builtin_bit_cast(half4, sone);

#pragma unroll 1
    for (int nt = 0; nt < 4; ++nt) {
        long px = px0 + w * 64 + nt * 16 + low;
        // q B-frag: 16B contiguous (k = c = q*8+j); values log2e-scaled
        short8 bq2 = *(const short8*)(qbase + px * 32 + q * 8);

        // single QK^T pass: f32 stash + folded row max (r5-verified)
        f32x4 dd[16];
        float m = -1e30f;
#pragma unroll
        for (int mt = 0; mt < 16; ++mt) {
            short8 ak = *(const short8*)(kA + mt * 512);
            dd[mt] = mfma_k32(ak, bq2, (f32x4){0.f, 0.f, 0.f, 0.f});
            m = fmaxf(fmaxf(dd[mt][0], dd[mt][1]), m);
            m = fmaxf(fmaxf(dd[mt][2], dd[mt][3]), m);
        }
        m = fmaxf(m, __shfl_xor(m, 16));
        m = fmaxf(m, __shfl_xor(m, 32));

        // exp2 from f32 stash, pack P to f16
        uint2v pk[16];
#pragma unroll
        for (int mt = 0; mt < 16; ++mt) {
            float p0 = exp2_raw(dd[mt][0] - m);
            float p1 = exp2_raw(dd[mt][1] - m);
            float p2 = exp2_raw(dd[mt][2] - m);
            float p3 = exp2_raw(dd[mt][3] - m);
            pk[mt][0] = pkrtz(p0, p1);
            pk[mt][1] = pkrtz(p2, p3);
        }

        // PV + ones-row denominator (both on the MFMA pipe)
        f32x4 o2[2], os;
        o2[0] = (f32x4){0.f, 0.f, 0.f, 0.f};
        o2[1] = (f32x4){0.f, 0.f, 0.f, 0.f};
        os    = (f32x4){0.f, 0.f, 0.f, 0.f};
        __builtin_amdgcn_s_setprio(1);
#pragma unroll
        for (int kc = 0; kc < 16; ++kc) {
            half4 pb = __builtin_bit_cast(half4, pk[kc]);
            half4 av0 = __builtin_bit_cast(half4, *(const sh4*)(vA + kc * 16));
            half4 av1 = __builtin_bit_cast(half4, *(const sh4*)(vA + 4224 + kc * 16));
            o2[0] = mfma_k16(av0, pb, o2[0]);
            o2[1] = mfma_k16(av1, pb, o2[1]);
            os    = mfma_k16(vones, pb, os);
        }
        __builtin_amdgcn_s_setprio(0);
        float inv = 1.0f / os[0];   // column sum for this lane's px

        // write out [b][c*8+h][px] fp32; D row=c=ct*16+q*4+r, col=px
#pragma unroll
        for (int ct = 0; ct < 2; ++ct)
#pragma unroll
            for (int r = 0; r < 4; ++r) {
                int c = ct * 16 + q * 4 + r;
                out[(((long)(b * 256 + c * 8 + h)) << 14) + px] = o2[ct][r] * inv;
            }
    }
}

// ---------------- launch ----------------
extern "C" void kernel_launch(void* const* d_in, const int* in_sizes, int n_in,
                              void* d_out, int out_size, void* d_ws, size_t ws_size,
                              hipStream_t stream) {
    const float* x  = (const float*)d_in[0];
    const float* Wq = (const float*)d_in[1];
    const float* bq = (const float*)d_in[2];
    const float* Wk = (const float*)d_in[3];
    const float* bk = (const float*)d_in[4];
    const float* Wv = (const float*)d_in[5];
    const float* bv = (const float*)d_in[6];
    float* out = (float*)d_out;

    char* ws = (char*)d_ws;
    const size_t OFF_XN = 0;             // 33,554,432  x NHWC f16
    const size_t OFF_Q  = 33554432;      // 33,554,432  q [b][h][px][c] f16 (log2e-scaled)
    const size_t OFF_WP = 67108864;      // 16,777,216  w_pack [512][16384] f16
    const size_t OFF_WQ = 83886080;      //    131,072  wq f16
    const size_t OFF_KP = 84017152;      //    524,288  k_pack f16
    const size_t OFF_VP = 84541440;      //    524,288  v_pack f16
    const size_t OFF_PT = 85065728;      // 16,777,216  partials fp32 [8][1024][512]
    const size_t NEEDED = 118620160;
    if (ws_size < NEEDED) return;        // fail loudly via validation

    short* xn  = (short*)(ws + OFF_XN);
    short* qp  = (short*)(ws + OFF_Q);
    short* wp  = (short*)(ws + OFF_WP);
    short* wqp = (short*)(ws + OFF_WQ);
    short* kp  = (short*)(ws + OFF_KP);
    short* vp  = (short*)(ws + OFF_VP);
    float* part= (float*)(ws + OFF_PT);

    k_pack_x <<<dim3(4096), dim3(256), 0, stream>>>(x, xn);
    k_pack_w <<<dim3(2048), dim3(256), 0, stream>>>(Wk, Wv, wp);
    k_pack_wq<<<dim3(256),  dim3(256), 0, stream>>>(Wq, wqp);
    k_kv_gemm<<<dim3(512),  dim3(256), 0, stream>>>(xn, wp, part);
    k_kv_fin <<<dim3(2048), dim3(256), 0, stream>>>(part, bk, bv, kp, vp);
    k_q_gemm <<<dim3(1024), dim3(256), 0, stream>>>(xn, wqp, bq, qp);
    k_attn   <<<dim3(2048), dim3(256), 0, stream>>>(qp, kp, vp, out);
}

// Round 20
// 142.959 us; speedup vs baseline: 1.1010x; 1.0248x over previous
//
#include <hip/hip_runtime.h>
#include <stdint.h>

// ---------------- types & helpers ----------------
typedef short sh4 __attribute__((ext_vector_type(4)));
typedef short short8 __attribute__((ext_vector_type(8)));
typedef float f32x4 __attribute__((ext_vector_type(4)));
typedef _Float16 half4 __attribute__((ext_vector_type(4)));
typedef _Float16 half8 __attribute__((ext_vector_type(8)));
typedef unsigned int uint2v __attribute__((ext_vector_type(2)));

__device__ __forceinline__ short f2h(float f) {
    _Float16 h = (_Float16)f;
    return __builtin_bit_cast(short, h);
}

__device__ __forceinline__ f32x4 mfma_k32(short8 a, short8 b, f32x4 c) {
    return __builtin_amdgcn_mfma_f32_16x16x32_f16(
        __builtin_bit_cast(half8, a), __builtin_bit_cast(half8, b), c, 0, 0, 0);
}
__device__ __forceinline__ f32x4 mfma_k16(half4 a, half4 b, f32x4 c) {
    return __builtin_amdgcn_mfma_f32_16x16x16f16(a, b, c, 0, 0, 0);
}
__device__ __forceinline__ unsigned int pkrtz(float a, float b) {
    return __builtin_bit_cast(unsigned int, __builtin_amdgcn_cvt_pkrtz(a, b));
}
__device__ __forceinline__ float exp2_raw(float x) {
    float r;
    asm("v_exp_f32 %0, %1" : "=v"(r) : "v"(x));   // 2^x, single instr
    return r;
}

// Problem constants: B=4, C=256, H=W=128 (PX=16384), inner=256, heads=8, c/head=32,
// patch=8 -> keys=256, conv K-dim = 256*64 = 16384.
// NOTE (r6/r14): exp shift must be the exact row max from the logits.
// NOTE (r9-r11): f16 logit stash -> wrong results (bisected). f32 stash is FINE
//   (r5/r18 passed). exp must run on f32 MFMA outputs.
// NOTE (r9 vs r10): ones-row MFMA denominator == shfl-sum (bit-identical);
//   verified passing since r16.
// NOTE (r16): q is PRE-SCALED by log2(e) in k_q_gemm -> raw v_exp_f32 in attn.
// NOTE (r17): Kl pitch-40 did NOT reduce SQ_LDS_BANK_CONFLICT -- b128 reads of
//   1KB/wave are structurally >=8 LDS phases; padding can't help. r20 removes
//   the K LDS reads entirely instead (kf[16] registers, r4/r5-verified path).
// NOTE (r19): kv_gemm address hoisting was neutral; kept (no harm).

// ---------------- pack kernels: 64x64 fp32 tile transpose -> f16 ----------------
__device__ __forceinline__ void transpose64(const float* __restrict__ src,
                                            short* __restrict__ dst,
                                            int srcSlowStride, int dstRowStride) {
    __shared__ float tile[64][65];
    const int t = threadIdx.x;
#pragma unroll
    for (int i = 0; i < 16; ++i) {
        int idx = i * 256 + t;
        int fast = idx & 63, slow = idx >> 6;
        tile[slow][fast] = src[(long)slow * srcSlowStride + fast];
    }
    __syncthreads();
#pragma unroll
    for (int i = 0; i < 2; ++i) {
        int ch = i * 256 + t;
        int fast = ch >> 3, sg = ch & 7;
        short8 v;
#pragma unroll
        for (int j = 0; j < 8; ++j) v[j] = f2h(tile[sg * 8 + j][fast]);
        *(short8*)(dst + (long)fast * dstRowStride + sg * 8) = v;
    }
}

// x: [4][256][16384] fp32 (NCHW) -> xn: [4][16384][256] f16 (NHWC)
__global__ __launch_bounds__(256) void k_pack_x(const float* __restrict__ x,
                                                short* __restrict__ xn) {
    int bi = blockIdx.x;                 // 4096 = 4b * 256pxt * 4ct
    int ct = bi & 3, pxt = (bi >> 2) & 255, b = bi >> 10;
    const float* src = x + (((long)(b * 256 + ct * 64)) << 14) + (long)pxt * 64;
    short* dst = xn + (((long)(b << 14) + pxt * 64) * 256) + ct * 64;
    transpose64(src, dst, 16384, 256);
}

// Wk/Wv: [256][256][64] fp32 -> wp: [512][64][256] f16 (oc<256: k, else v), K order (dydx, c)
__global__ __launch_bounds__(256) void k_pack_w(const float* __restrict__ wk,
                                                const float* __restrict__ wv,
                                                short* __restrict__ wp) {
    int bi = blockIdx.x;                 // 2048 = 512oc * 4ct
    int ct = bi & 3, oc = bi >> 2;
    const float* base = (oc < 256) ? (wk + (long)oc * 16384) : (wv + (long)(oc - 256) * 16384);
    const float* src = base + ct * 4096; // + c0*64
    short* dst = wp + (long)oc * 16384 + ct * 64;
    transpose64(src, dst, 64, 256);
}

// Wq: [256][256] fp32 -> f16 (layout preserved: [oc][c])
__global__ __launch_bounds__(256) void k_pack_wq(const float* __restrict__ wq,
                                                 short* __restrict__ wqp) {
    int i = blockIdx.x * 256 + threadIdx.x; // grid 256 -> 65536
    wqp[i] = f2h(wq[i]);
}

// ---------------- K/V conv as GEMM (128x64 tile, 512 blocks, 2/CU) ----
// C[patch 1024][oc 512] = A[patch][k 16384] * B[k][oc]
// grid 512 = 8kc * 8pm * 8nb; block 256 thr (4 waves); Kchunk 2048.
// kk-loop: 8 outer kk4 (addresses hoisted) x 4 unrolled j (imm offsets).
__global__ __launch_bounds__(256) void k_kv_gemm(const short* __restrict__ xn,
                                                 const short* __restrict__ wp,
                                                 float* __restrict__ part) {
    __shared__ short Al[128 * 64]; // rows 128B = 8 granules, swizzled
    __shared__ short Bl[64 * 64];
    int bid = blockIdx.x;                       // 512
    int wg = (bid & 7) * 64 + (bid >> 3);       // XCD-contiguous swizzle (512 = 8*64)
    int nb = wg & 7, pm = (wg >> 3) & 7, kc = wg >> 6;
    int t = threadIdx.x, l = t & 63, w = t >> 6;
    int wm = w >> 1, wn = w & 1;
    int low = l & 15, q = l >> 4;

    // LDS staging addresses (loop-invariant)
    short* lda[4];
    short* ldb[2];
#pragma unroll
    for (int i = 0; i < 4; ++i) {
        int g = i * 256 + t;
        int row = g >> 3, lg = g & 7;
        lda[i] = Al + row * 64 + ((lg ^ (row & 7)) * 8);
    }
#pragma unroll
    for (int i = 0; i < 2; ++i) {
        int g = i * 256 + t;
        int row = g >> 3, lg = g & 7;
        ldb[i] = Bl + row * 64 + ((lg ^ (row & 7)) * 8);
    }

    f32x4 acc[4][2];
#pragma unroll
    for (int mt = 0; mt < 4; ++mt)
#pragma unroll
        for (int nt = 0; nt < 2; ++nt) acc[mt][nt] = (f32x4){0.f, 0.f, 0.f, 0.f};

#pragma unroll 1
    for (int kk4 = 0; kk4 < 8; ++kk4) {
        // A/B base pointers for this kk4 (dydx = kc*8 + kk4 constant; j adds 64 shorts)
        const short* apt[4];
        const short* bpt[2];
        int dydx = kc * 8 + kk4;
#pragma unroll
        for (int i = 0; i < 4; ++i) {
            int g = i * 256 + t;
            int row = g >> 3, lg = g & 7;
            int patch = pm * 128 + row;
            int bb = patch >> 8, pid = patch & 255;
            int ph = pid >> 4, pw = pid & 15;
            int px = (ph * 8 + (dydx >> 3)) * 128 + pw * 8 + (dydx & 7);
            apt[i] = xn + ((long)(bb << 14) + px) * 256 + lg * 8;
        }
#pragma unroll
        for (int i = 0; i < 2; ++i) {
            int g = i * 256 + t;
            int row = g >> 3, lg = g & 7;
            int oc = nb * 64 + row;
            bpt[i] = wp + (long)oc * 16384 + kc * 2048 + kk4 * 256 + lg * 8;
        }
#pragma unroll
        for (int j = 0; j < 4; ++j) {
            short8 va[4], vb[2];
#pragma unroll
            for (int i = 0; i < 4; ++i) va[i] = *(const short8*)(apt[i] + j * 64);
#pragma unroll
            for (int i = 0; i < 2; ++i) vb[i] = *(const short8*)(bpt[i] + j * 64);
#pragma unroll
            for (int i = 0; i < 4; ++i) *(short8*)lda[i] = va[i];
#pragma unroll
            for (int i = 0; i < 2; ++i) *(short8*)ldb[i] = vb[i];
            __syncthreads();
#pragma unroll
            for (int ks = 0; ks < 2; ++ks) {
                short8 af[4], bf[2];
#pragma unroll
                for (int mt = 0; mt < 4; ++mt) {
                    int row = wm * 64 + mt * 16 + low;
                    int lg = ks * 4 + q;
                    af[mt] = *(const short8*)(Al + row * 64 + ((lg ^ (row & 7)) * 8));
                }
#pragma unroll
                for (int nt = 0; nt < 2; ++nt) {
                    int row = wn * 32 + nt * 16 + low;
                    int lg = ks * 4 + q;
                    bf[nt] = *(const short8*)(Bl + row * 64 + ((lg ^ (row & 7)) * 8));
                }
#pragma unroll
                for (int mt = 0; mt < 4; ++mt)
#pragma unroll
                    for (int nt = 0; nt < 2; ++nt)
                        acc[mt][nt] = mfma_k32(af[mt], bf[nt], acc[mt][nt]);
            }
            __syncthreads();
        }
    }
    // D: row(patch) = q*4+r (+16mt+64wm+128pm), col(oc) = low (+16nt+32wn+64nb)
#pragma unroll
    for (int mt = 0; mt < 4; ++mt) {
        int patch = pm * 128 + wm * 64 + mt * 16 + q * 4;
#pragma unroll
        for (int nt = 0; nt < 2; ++nt) {
            int oc = nb * 64 + wn * 32 + nt * 16 + low;
#pragma unroll
            for (int r = 0; r < 4; ++r)
                part[((long)kc * 1024 + patch + r) * 512 + oc] = acc[mt][nt][r];
        }
    }
}

// reduce partials, add bias, pack k -> [b][h][key][c], v -> [b][h][c][key] (f16)
__global__ __launch_bounds__(256) void k_kv_fin(const float* __restrict__ part,
                                                const float* __restrict__ bk,
                                                const float* __restrict__ bv,
                                                short* __restrict__ kp,
                                                short* __restrict__ vp) {
    int idx = blockIdx.x * 256 + threadIdx.x;   // 524288 = 1024patch * 512oc
    int oc = idx & 511, patch = idx >> 9;
    float s = 0.f;
#pragma unroll
    for (int kc = 0; kc < 8; ++kc) s += part[(long)kc * 524288 + idx];
    int b = patch >> 8, key = patch & 255;
    if (oc < 256) {
        s += bk[oc];
        kp[(((long)(b * 8 + (oc & 7)) * 256) + key) * 32 + (oc >> 3)] = f2h(s);
    } else {
        int o = oc - 256;
        s += bv[o];
        vp[(((long)(b * 8 + (o & 7)) * 32) + (o >> 3)) * 256 + key] = f2h(s);
    }
}

// ---------------- Q conv (1x1) as GEMM (no staging LDS, D[px][oc]) -------
// A-frag = xn[px][c], B-frag = wqp[oc][c] (L2-hot). grid 1024; 4 waves.
// q stored as [b][h 8][px 16384][c 32] f16, PRE-SCALED by log2(e) (r16 note).
__global__ __launch_bounds__(256) void k_q_gemm(const short* __restrict__ xn,
                                                const short* __restrict__ wqp,
                                                const float* __restrict__ bq,
                                                short* __restrict__ qp) {
    __shared__ short Tb[64 * 256];  // 32 KB
    int bi = blockIdx.x;            // 1024 = 4b * 256 tiles
    int b = bi >> 8, tile = bi & 255;
    long px0 = (long)tile * 64;
    int t = threadIdx.x, l = t & 63, w = t >> 6;
    int low = l & 15, q = l >> 4;

    const short* xb = xn + (((long)(b << 14)) + px0) * 256;

    float bqv[4];
#pragma unroll
    for (int nt = 0; nt < 4; ++nt) bqv[nt] = bq[w * 64 + nt * 16 + low];

    f32x4 acc[4][4];   // [mt: px][nt: oc]
#pragma unroll
    for (int mt = 0; mt < 4; ++mt)
#pragma unroll
        for (int nt = 0; nt < 4; ++nt) acc[mt][nt] = (f32x4){0.f, 0.f, 0.f, 0.f};

#pragma unroll
    for (int kstep = 0; kstep < 8; ++kstep) {
        short8 af[4], bf[4];
#pragma unroll
        for (int mt = 0; mt < 4; ++mt)
            af[mt] = *(const short8*)(xb + (mt * 16 + low) * 256 + kstep * 32 + q * 8);
#pragma unroll
        for (int nt = 0; nt < 4; ++nt)
            bf[nt] = *(const short8*)(wqp + (w * 64 + nt * 16 + low) * 256 + kstep * 32 + q * 8);
#pragma unroll
        for (int mt = 0; mt < 4; ++mt)
#pragma unroll
            for (int nt = 0; nt < 4; ++nt)
                acc[mt][nt] = mfma_k32(af[mt], bf[nt], acc[mt][nt]);
    }
    // D: px = mt*16 + q*4 + r, oc = w*64 + nt*16 + low.
    // Tb[px][h 8][c 32] pitch 256 shorts; 16B-granule index XOR (px&7).
    const float LOG2E = 1.44269504088896f;
#pragma unroll
    for (int mt = 0; mt < 4; ++mt)
#pragma unroll
        for (int nt = 0; nt < 4; ++nt) {
            int oc = w * 64 + nt * 16 + low;
            int h8 = oc & 7, cc = oc >> 3;
            int gi = h8 * 4 + (cc >> 3);          // 16B granule 0..31 within row
#pragma unroll
            for (int r = 0; r < 4; ++r) {
                int px = mt * 16 + q * 4 + r;
                Tb[px * 256 + ((gi ^ (px & 7)) * 8) + (cc & 7)] =
                    f2h((acc[mt][nt][r] + bqv[nt]) * LOG2E);
            }
        }
    __syncthreads();
#pragma unroll
    for (int i = 0; i < 8; ++i) {
        int g = i * 256 + t;            // 2048 chunks of 16B
        int pxl = g >> 5, g16 = g & 31; // g16 = hh*4 + oct
        int hh = g16 >> 2, oct = g16 & 3;
        short8 v = *(const short8*)(Tb + pxl * 256 + ((g16 ^ (pxl & 7)) * 8));
        *(short8*)(qp + (((long)(b * 8 + hh) * 16384) + px0 + pxl) * 32 + oct * 8) = v;
    }
}

// ---------------- fused attention (v15: K in registers, V-only LDS) ----
// grid 2048 = 4b * 8h * 64 tiles of 256px; block 256 thr = 4 waves x 64 px.
// K-frags held in kf[16] registers, loaded once per block straight from the
// L2-hot 16KB kp tile (r4/r5-verified load pattern) -> removes 64 structurally
// multi-phase b128 LDS reads per block + the K staging pass + 16KB LDS.
// Single-pass QK^T with f32 dd[16] stash; exp2 on f32 outputs; ones-row
// MFMA denominator; setprio around PV.
__global__ __launch_bounds__(256) void k_attn(const short* __restrict__ qp,
                                              const short* __restrict__ kp,
                                              const short* __restrict__ vp,
                                              float* __restrict__ out) {
    __shared__ short Vl[32 * 264];   // 16.9 KB (V only)
    int bi = blockIdx.x;
    int tile = bi & 63, h = (bi >> 6) & 7, b = bi >> 9;
    int bh = b * 8 + h;
    long px0 = (long)tile * 256;
    int t = threadIdx.x, l = t & 63, w = t >> 6;
    int low = l & 15, q = l >> 4;

    const short* kbase = kp + (long)bh * 8192;    // [key 256][c 32]
    const short* vbase = vp + (long)bh * 8192;    // [c 32][key 256]
    const short* qbase = qp + (long)bh * 16384 * 32;  // [px][c 32]

    // stage V -> LDS (pitch 264)
#pragma unroll
    for (int i = 0; i < 4; ++i) {
        int g = i * 256 + t;
        int c = g >> 5, k8 = g & 31;
        *(short8*)(Vl + c * 264 + k8 * 8) = *(const short8*)(vbase + c * 256 + k8 * 8);
    }
    // K fragments -> registers (loaded once, reused by all 4 nt; L2-hot tile)
    short8 kf[16];
#pragma unroll
    for (int mt = 0; mt < 16; ++mt)
        kf[mt] = *(const short8*)(kbase + (mt * 16 + low) * 32 + q * 8);
    __syncthreads();

    const short* vA = Vl + low * 264 + q * 4;  // + ct*4224 + kc*16 (imm offset)
    const sh4 sone = {0x3C00, 0x3C00, 0x3C00, 0x3C00};
    const half4 vones = __builtin_bit_cast(half4, sone);

#pragma unroll 1
    for (int nt = 0; nt < 4; ++nt) {
        long px = px0 + w * 64 + nt * 16 + low;
        // q B-frag: 16B contiguous (k = c = q*8+j); values log2e-scaled
        short8 bq2 = *(const short8*)(qbase + px * 32 + q * 8);

        // single QK^T pass: f32 stash + folded row max (r5/r18-verified)
        f32x4 dd[16];
        float m = -1e30f;
#pragma unroll
        for (int mt = 0; mt < 16; ++mt) {
            dd[mt] = mfma_k32(kf[mt], bq2, (f32x4){0.f, 0.f, 0.f, 0.f});
            m = fmaxf(fmaxf(dd[mt][0], dd[mt][1]), m);
            m = fmaxf(fmaxf(dd[mt][2], dd[mt][3]), m);
        }
        m = fmaxf(m, __shfl_xor(m, 16));
        m = fmaxf(m, __shfl_xor(m, 32));

        // exp2 from f32 stash, pack P to f16
        uint2v pk[16];
#pragma unroll
        for (int mt = 0; mt < 16; ++mt) {
            float p0 = exp2_raw(dd[mt][0] - m);
            float p1 = exp2_raw(dd[mt][1] - m);
            float p2 = exp2_raw(dd[mt][2] - m);
            float p3 = exp2_raw(dd[mt][3] - m);
            pk[mt][0] = pkrtz(p0, p1);
            pk[mt][1] = pkrtz(p2, p3);
        }

        // PV + ones-row denominator (both on the MFMA pipe)
        f32x4 o2[2], os;
        o2[0] = (f32x4){0.f, 0.f, 0.f, 0.f};
        o2[1] = (f32x4){0.f, 0.f, 0.f, 0.f};
        os    = (f32x4){0.f, 0.f, 0.f, 0.f};
        __builtin_amdgcn_s_setprio(1);
#pragma unroll
        for (int kc = 0; kc < 16; ++kc) {
            half4 pb = __builtin_bit_cast(half4, pk[kc]);
            half4 av0 = __builtin_bit_cast(half4, *(const sh4*)(vA + kc * 16));
            half4 av1 = __builtin_bit_cast(half4, *(const sh4*)(vA + 4224 + kc * 16));
            o2[0] = mfma_k16(av0, pb, o2[0]);
            o2[1] = mfma_k16(av1, pb, o2[1]);
            os    = mfma_k16(vones, pb, os);
        }
        __builtin_amdgcn_s_setprio(0);
        float inv = 1.0f / os[0];   // column sum for this lane's px

        // write out [b][c*8+h][px] fp32; D row=c=ct*16+q*4+r, col=px
#pragma unroll
        for (int ct = 0; ct < 2; ++ct)
#pragma unroll
            for (int r = 0; r < 4; ++r) {
                int c = ct * 16 + q * 4 + r;
                out[(((long)(b * 256 + c * 8 + h)) << 14) + px] = o2[ct][r] * inv;
            }
    }
}

// ---------------- launch ----------------
extern "C" void kernel_launch(void* const* d_in, const int* in_sizes, int n_in,
                              void* d_out, int out_size, void* d_ws, size_t ws_size,
                              hipStream_t stream) {
    const float* x  = (const float*)d_in[0];
    const float* Wq = (const float*)d_in[1];
    const float* bq = (const float*)d_in[2];
    const float* Wk = (const float*)d_in[3];
    const float* bk = (const float*)d_in[4];
    const float* Wv = (const float*)d_in[5];
    const float* bv = (const float*)d_in[6];
    float* out = (float*)d_out;

    char* ws = (char*)d_ws;
    const size_t OFF_XN = 0;             // 33,554,432  x NHWC f16
    const size_t OFF_Q  = 33554432;      // 33,554,432  q [b][h][px][c] f16 (log2e-scaled)
    const size_t OFF_WP = 67108864;      // 16,777,216  w_pack [512][16384] f16
    const size_t OFF_WQ = 83886080;      //    131,072  wq f16
    const size_t OFF_KP = 84017152;      //    524,288  k_pack f16
    const size_t OFF_VP = 84541440;      //    524,288  v_pack f16
    const size_t OFF_PT = 85065728;      // 16,777,216  partials fp32 [8][1024][512]
    const size_t NEEDED = 118620160;
    if (ws_size < NEEDED) return;        // fail loudly via validation

    short* xn  = (short*)(ws + OFF_XN);
    short* qp  = (short*)(ws + OFF_Q);
    short* wp  = (short*)(ws + OFF_WP);
    short* wqp = (short*)(ws + OFF_WQ);
    short* kp  = (short*)(ws + OFF_KP);
    short* vp  = (short*)(ws + OFF_VP);
    float* part= (float*)(ws + OFF_PT);

    k_pack_x <<<dim3(4096), dim3(256), 0, stream>>>(x, xn);
    k_pack_w <<<dim3(2048), dim3(256), 0, stream>>>(Wk, Wv, wp);
    k_pack_wq<<<dim3(256),  dim3(256), 0, stream>>>(Wq, wqp);
    k_kv_gemm<<<dim3(512),  dim3(256), 0, stream>>>(xn, wp, part);
    k_kv_fin <<<dim3(2048), dim3(256), 0, stream>>>(part, bk, bv, kp, vp);
    k_q_gemm <<<dim3(1024), dim3(256), 0, stream>>>(xn, wqp, bq, qp);
    k_attn   <<<dim3(2048), dim3(256), 0, stream>>>(qp, kp, vp, out);
}